// Round 8
// baseline (557.284 us; speedup 1.0000x reference)
//
#include <hip/hip_runtime.h>
#include <stdint.h>

// GATConv fused v8: back to v5's wave-local structure, but 2 blocks/CU.
// 256-thread blocks, BR=64, single-buffered K/V, P overlaid on the K region
// (K dead after S phase; lgkm-only rendezvous B2 — no DMA outstanding there).
// LDS = 64 KB/block -> 2 co-resident blocks cover each other's stalls.
// Diet kept: packed-f16x2 max reduce, deferred l-sum, pswz P swizzle.

typedef _Float16 f16;
typedef unsigned short u16;
typedef __attribute__((ext_vector_type(8))) _Float16 f16x8;
typedef __attribute__((ext_vector_type(4))) _Float16 f16x4;
typedef __attribute__((ext_vector_type(4))) float f32x4;

#define NN 8192
#define DD 256
#define BR 64
#define BC 64
#define CCH 4
#define COLS (NN / CCH)  // 2048
#define NIT (COLS / BC)  // 32

#define MFMA(a, b, c) __builtin_amdgcn_mfma_f32_16x16x32_f16((a), (b), (c), 0, 0, 0)

// wave-sync WITHOUT vmcnt drain (safe only when no DMA is outstanding).
#define LGKM_BARRIER() __asm__ __volatile__("s_waitcnt lgkmcnt(0)\ns_barrier" ::: "memory")

__device__ __forceinline__ void gl2lds16(const void* g, void* l) {
    __builtin_amdgcn_global_load_lds(
        (const __attribute__((address_space(1))) unsigned int*)g,
        (__attribute__((address_space(3))) unsigned int*)l, 16, 0, 0);
}

__device__ __forceinline__ u16 f16bits(f16 h) {
    union { f16 h; u16 u; } c;
    c.h = h;
    return c.u;
}

union F16x2U {
    unsigned u;
    struct { f16 lo, hi; } f;
};

// P row swizzle: 4 distinct 16B-block offsets across the quads of a C-layout write
__device__ __forceinline__ int pswz(int row) { return (row ^ (row >> 2)) & 7; }

// ---------------- split X to fp16 hi/lo (4 elems/thread) ----------------
__global__ void splitX_kernel(const float4* __restrict__ X, f16x4* __restrict__ Xh,
                              f16x4* __restrict__ Xl) {
    const int i = blockIdx.x * blockDim.x + threadIdx.x;  // 524288
    const float4 v = X[i];
    const f16 h0 = (f16)v.x, h1 = (f16)v.y, h2 = (f16)v.z, h3 = (f16)v.w;
    f16x4 H = {h0, h1, h2, h3};
    f16x4 L = {(f16)(v.x - (float)h0), (f16)(v.y - (float)h1), (f16)(v.z - (float)h2),
               (f16)(v.w - (float)h3)};
    Xh[i] = H;
    Xl[i] = L;
}

// W[k][n] (3 mats 256x256) -> Wt[(mat*256+n)][k] fp16 hi/lo (transposed)
__global__ void splitW_kernel(const float* __restrict__ Wq, const float* __restrict__ Wk,
                              const float* __restrict__ Wv, f16* __restrict__ WtH,
                              f16* __restrict__ WtL) {
    const int i = blockIdx.x * blockDim.x + threadIdx.x;  // 3*65536
    const int mat = i >> 16;
    const int k = (i >> 8) & 255;
    const int n = i & 255;
    const float* W = (mat == 0) ? Wq : ((mat == 1) ? Wk : Wv);
    const float v = W[k * 256 + n];
    const f16 h = (f16)v;
    const size_t o = (size_t)(mat * 256 + n) * 256 + k;
    WtH[o] = h;
    WtL[o] = (f16)(v - (float)h);
}

// ---------------- QKV GEMM: LDS-staged W chunks, X frags in registers ----------------
__global__ __launch_bounds__(256, 2) void qkv_kernel(
    const f16* __restrict__ Xh, const f16* __restrict__ Xl,
    const f16* __restrict__ WtH, const f16* __restrict__ WtL,
    f16* __restrict__ Qh, f16* __restrict__ Ql,
    f16* __restrict__ Kh, f16* __restrict__ Vt) {
    __shared__ f16 Wh[64 * 256];
    __shared__ f16 Wl[64 * 256];
    const int lane = threadIdx.x & 63;
    const int w = threadIdx.x >> 6;
    const int l15 = lane & 15;
    const int quad = lane >> 4;
    const int r0 = blockIdx.x * 64;
    const int mat = blockIdx.y;

    f16x8 xh[8], xl[8];
    const size_t xb = (size_t)(r0 + w * 16 + l15) * DD + quad * 8;
#pragma unroll
    for (int kc = 0; kc < 8; ++kc) {
        xh[kc] = *(const f16x8*)(Xh + xb + kc * 32);
        xl[kc] = *(const f16x8*)(Xl + xb + kc * 32);
    }
    const int orow = r0 + w * 16 + quad * 4;

#pragma unroll 1
    for (int c = 0; c < 4; ++c) {
        const int nb = mat * 256 + c * 64;
#pragma unroll
        for (int i = 0; i < 8; ++i) {
            const int r = w * 16 + i * 2 + (lane >> 5);
            gl2lds16(WtH + (size_t)(nb + r) * DD + (((lane & 31) ^ (r & 7)) * 8),
                     &Wh[(w * 16 + i * 2) * 256]);
        }
#pragma unroll
        for (int i = 0; i < 8; ++i) {
            const int r = w * 16 + i * 2 + (lane >> 5);
            gl2lds16(WtL + (size_t)(nb + r) * DD + (((lane & 31) ^ (r & 7)) * 8),
                     &Wl[(w * 16 + i * 2) * 256]);
        }
        __syncthreads();

        const f32x4 fzero = {0.f, 0.f, 0.f, 0.f};
        f32x4 acc[4];
#pragma unroll
        for (int nt = 0; nt < 4; ++nt) acc[nt] = fzero;
#pragma unroll
        for (int kc = 0; kc < 8; ++kc)
#pragma unroll
            for (int nt = 0; nt < 4; ++nt) {
                const int r = nt * 16 + l15;
                const int blk = (((kc * 4 + quad) ^ (r & 7)) * 8);
                const f16x8 wh = *(const f16x8*)&Wh[r * 256 + blk];
                const f16x8 wl = *(const f16x8*)&Wl[r * 256 + blk];
                acc[nt] = MFMA(xh[kc], wh, acc[nt]);
                acc[nt] = MFMA(xh[kc], wl, acc[nt]);
                acc[nt] = MFMA(xl[kc], wh, acc[nt]);
            }

        if (mat == 0) {
#pragma unroll
            for (int nt = 0; nt < 4; ++nt)
#pragma unroll
                for (int rg = 0; rg < 4; ++rg) {
                    const int col = c * 64 + nt * 16 + l15;
                    const float v = acc[nt][rg];
                    const f16 h = (f16)v;
                    Qh[(size_t)(orow + rg) * DD + col] = h;
                    Ql[(size_t)(orow + rg) * DD + col] = (f16)(v - (float)h);
                }
        } else if (mat == 1) {
#pragma unroll
            for (int nt = 0; nt < 4; ++nt)
#pragma unroll
                for (int rg = 0; rg < 4; ++rg) {
                    const int col = c * 64 + nt * 16 + l15;
                    Kh[(size_t)(orow + rg) * DD + col] = (f16)acc[nt][rg];
                }
        } else {
#pragma unroll
            for (int nt = 0; nt < 4; ++nt) {
                const int n = c * 64 + nt * 16 + l15;
                ushort4 pk;
                pk.x = f16bits((f16)acc[nt][0]);
                pk.y = f16bits((f16)acc[nt][1]);
                pk.z = f16bits((f16)acc[nt][2]);
                pk.w = f16bits((f16)acc[nt][3]);
                *(ushort4*)(Vt + (size_t)n * NN + orow) = pk;
            }
        }
        __syncthreads();
    }
}

// ---------------- flash kernel v8 ----------------
// grid 512 linear: cch = bid&3 (L2 pinning), rowblk = bid>>2, BR=64, 4 waves.
// Wave w owns rows w*16..+16 for S, softmax AND PV (all wave-local).
// Single-buffered K/V; P overlaid on K region (K dead after B2).
__global__ __launch_bounds__(256, 2) void flash_kernel(
    const f16* __restrict__ Qh, const f16* __restrict__ Ql,
    const f16* __restrict__ Kh, const f16* __restrict__ Vt,
    const int* __restrict__ A,
    float* __restrict__ pO, float* __restrict__ pM, float* __restrict__ pL) {
    __shared__ f16 Klds[64 * 256];  // 32 KB, [j][k] XOR-swizzled; P overlays after S
    __shared__ f16 Vlds[256 * 64];  // 32 KB, [n][j] swizzled by n&7

    const int lane = threadIdx.x & 63;
    const int w = threadIdx.x >> 6;  // 0..3
    const int l15 = lane & 15;
    const int quad = lane >> 4;
    const int bid = blockIdx.x;
    const int cch = bid & 3;
    const int r0 = (bid >> 2) * BR;
    const int col0 = cch * COLS;

    // Q fragments resident (A-layout m=l15, k=quad*8+i), hi+lo; rows w*16..+16
    f16x8 qh[8], ql[8];
    {
        const size_t qb = (size_t)(r0 + w * 16 + l15) * DD + quad * 8;
#pragma unroll
        for (int kc = 0; kc < 8; ++kc) {
            qh[kc] = *(const f16x8*)(Qh + qb + kc * 32);
            ql[kc] = *(const f16x8*)(Ql + qb + kc * 32);
        }
    }

    const f32x4 fzero = {0.f, 0.f, 0.f, 0.f};
    f32x4 accO[16];
#pragma unroll
    for (int i = 0; i < 16; ++i) accO[i] = fzero;
    float mrow[4], lpart[4];  // lpart: per-LANE partial sums, reduced in epilogue
#pragma unroll
    for (int r = 0; r < 4; ++r) {
        mrow[r] = -1e30f;
        lpart[r] = 0.f;
    }
    const int srow = r0 + w * 16 + quad * 4;  // global row base (softmax/PV)

#pragma unroll 1
    for (int it = 0; it < NIT; ++it) {
        const int j0 = col0 + it * BC;

        // stage K tile rows w*16..+16 and V tile n-rows w*64..+64 (single buffer)
#pragma unroll
        for (int i = 0; i < 8; ++i) {
            const int r = w * 16 + i * 2 + (lane >> 5);
            gl2lds16(Kh + (size_t)(j0 + r) * DD + (((lane & 31) ^ (r & 7)) * 8),
                     &Klds[(w * 16 + i * 2) * 256]);
        }
#pragma unroll
        for (int i = 0; i < 8; ++i) {
            const int n = w * 64 + i * 8 + (lane >> 3);
            gl2lds16(Vt + (size_t)n * NN + j0 + (((lane & 7) ^ (n & 7)) * 8),
                     &Vlds[(w * 64 + i * 8) * 64]);
        }

        // adjacency for this tile (issued pre-barrier; drained by B1 with the DMA)
        int av[4][4];
#pragma unroll
        for (int rgi = 0; rgi < 4; ++rgi)
#pragma unroll
            for (int jt = 0; jt < 4; ++jt)
                av[rgi][jt] = __builtin_nontemporal_load(
                    A + (size_t)(srow + rgi) * NN + j0 + jt * 16 + l15);

        __syncthreads();  // B1: staging visible (other CU-resident block computes)

        // S = (Qh+Ql)·Kh^T : 16 rows x 64 cols per wave
        f32x4 accS[4];
#pragma unroll
        for (int jt = 0; jt < 4; ++jt) accS[jt] = fzero;
#pragma unroll
        for (int kc = 0; kc < 8; ++kc)
#pragma unroll
            for (int jt = 0; jt < 4; ++jt) {
                const int r = jt * 16 + l15;
                const f16x8 kf =
                    *(const f16x8*)&Klds[r * 256 + (((kc * 4 + quad) ^ (r & 7)) * 8)];
                accS[jt] = MFMA(qh[kc], kf, accS[jt]);
                accS[jt] = MFMA(ql[kc], kf, accS[jt]);
            }

        // B2: all waves' K reads done -> K region reusable for P.
        // lgkm-only is safe: no DMA outstanding (drained at B1).
        LGKM_BARRIER();

        // mask + per-lane jt-max
        float mx[4];
#pragma unroll
        for (int rgi = 0; rgi < 4; ++rgi) {
            const int gr = srow + rgi;
            float m = -3.0e38f;
#pragma unroll
            for (int jt = 0; jt < 4; ++jt) {
                const int gc = j0 + jt * 16 + l15;
                const float s = (av[rgi][jt] != 0 || gr == gc) ? accS[jt][rgi] : -3.0e38f;
                accS[jt][rgi] = s;
                m = fmaxf(m, s);
            }
            mx[rgi] = m;
        }
        // packed f16x2 max reduction over 16 lanes (2 chains instead of 4)
        {
            F16x2U a, b;
            a.f.lo = (f16)mx[0];
            a.f.hi = (f16)mx[1];
            b.f.lo = (f16)mx[2];
            b.f.hi = (f16)mx[3];
#pragma unroll
            for (int off = 1; off < 16; off <<= 1) {
                F16x2U as, bs;
                as.u = __shfl_xor(a.u, off, 64);
                bs.u = __shfl_xor(b.u, off, 64);
                a.f.lo = (as.f.lo > a.f.lo) ? as.f.lo : a.f.lo;
                a.f.hi = (as.f.hi > a.f.hi) ? as.f.hi : a.f.hi;
                b.f.lo = (bs.f.lo > b.f.lo) ? bs.f.lo : b.f.lo;
                b.f.hi = (bs.f.hi > b.f.hi) ? bs.f.hi : b.f.hi;
            }
            mx[0] = (float)a.f.lo;
            mx[1] = (float)a.f.hi;
            mx[2] = (float)b.f.lo;
            mx[3] = (float)b.f.hi;
        }

        float alpha[4];
#pragma unroll
        for (int rgi = 0; rgi < 4; ++rgi) {
            const float mnew = fmaxf(mrow[rgi], mx[rgi]);
            alpha[rgi] = __expf(mrow[rgi] - mnew);
            mrow[rgi] = mnew;
            float rs = 0.f;
            const int lrow = w * 16 + quad * 4 + rgi;  // local P row (0..63)
#pragma unroll
            for (int jt = 0; jt < 4; ++jt) {
                const float s = accS[jt][rgi];
                const float e = (s > -1.0e37f) ? __expf(s - mnew) : 0.f;
                rs += e;
                const int col = jt * 16 + l15;
                // P overlay in K region: row stride 256 f16, pswz 16B-block swizzle
                Klds[lrow * 256 + (((col >> 3) ^ pswz(lrow)) * 8) + (col & 7)] = (f16)e;
            }
            lpart[rgi] = lpart[rgi] * alpha[rgi] + rs;
        }
#pragma unroll
        for (int nt = 0; nt < 16; ++nt)
#pragma unroll
            for (int rgi = 0; rgi < 4; ++rgi) accO[nt][rgi] *= alpha[rgi];

        // P A-frags from own rows (in-order per-wave LDS: no barrier needed)
        f16x8 pf[2];
        {
            const int rr = w * 16 + l15;
            pf[0] = *(const f16x8*)&Klds[rr * 256 + (((0 + quad) ^ pswz(rr)) * 8)];
            pf[1] = *(const f16x8*)&Klds[rr * 256 + (((4 + quad) ^ pswz(rr)) * 8)];
        }

        // PV: 16 rows x 256 n per wave
#pragma unroll
        for (int nt = 0; nt < 16; ++nt)
#pragma unroll
            for (int kc2 = 0; kc2 < 2; ++kc2) {
                const int n = nt * 16 + l15;
                const f16x8 vf =
                    *(const f16x8*)&Vlds[n * 64 + (((kc2 * 4 + quad) ^ (n & 7)) * 8)];
                accO[nt] = MFMA(pf[kc2], vf, accO[nt]);
            }

        __syncthreads();  // B3: V/P reads done; LDS free for next iter's staging
    }

    // epilogue: reduce per-lane l partials across 16 lanes
#pragma unroll
    for (int rgi = 0; rgi < 4; ++rgi)
#pragma unroll
        for (int off = 1; off < 16; off <<= 1)
            lpart[rgi] += __shfl_xor(lpart[rgi], off, 64);

    // write partials
#pragma unroll
    for (int nt = 0; nt < 16; ++nt)
#pragma unroll
        for (int rgi = 0; rgi < 4; ++rgi)
            pO[((size_t)cch * NN + srow + rgi) * DD + nt * 16 + l15] = accO[nt][rgi];
    if (l15 == 0) {
#pragma unroll
        for (int rgi = 0; rgi < 4; ++rgi) {
            pM[(size_t)cch * NN + srow + rgi] = mrow[rgi];
            pL[(size_t)cch * NN + srow + rgi] = lpart[rgi];
        }
    }
}

// ---------------- merge partials (8 rows/block) ----------------
__global__ __launch_bounds__(256) void merge_kernel(const float* __restrict__ pO,
                                                    const float* __restrict__ pM,
                                                    const float* __restrict__ pL,
                                                    float* __restrict__ out) {
    const int n = threadIdx.x;
#pragma unroll 1
    for (int rr = 0; rr < 8; ++rr) {
        const int row = blockIdx.x * 8 + rr;
        float mc[CCH], lc[CCH];
        float M = -3e38f;
#pragma unroll
        for (int c = 0; c < CCH; ++c) {
            mc[c] = pM[(size_t)c * NN + row];
            lc[c] = pL[(size_t)c * NN + row];
            M = fmaxf(M, mc[c]);
        }
        float L = 0.f, acc = 0.f;
#pragma unroll
        for (int c = 0; c < CCH; ++c) {
            const float wgt = __expf(mc[c] - M);
            L += wgt * lc[c];
            acc += wgt * pO[((size_t)c * NN + row) * DD + n];
        }
        out[(size_t)row * DD + n] = acc / L;
    }
}

extern "C" void kernel_launch(void* const* d_in, const int* in_sizes, int n_in,
                              void* d_out, int out_size, void* d_ws, size_t ws_size,
                              hipStream_t stream) {
    const float* X = (const float*)d_in[0];
    const int* A = (const int*)d_in[1];
    const float* Wq = (const float*)d_in[2];
    const float* Wk = (const float*)d_in[3];
    const float* Wv = (const float*)d_in[4];
    float* out = (float*)d_out;

    char* ws = (char*)d_ws;
    const size_t MB = 1ull << 20;
    f16* Xh = (f16*)(ws + 0 * MB);
    f16* Xl = (f16*)(ws + 4 * MB);
    f16* WtH = (f16*)(ws + 8 * MB);
    f16* WtL = (f16*)(ws + 8 * MB + 512 * 1024);
    f16* Qh = (f16*)(ws + 9 * MB);
    f16* Ql = (f16*)(ws + 13 * MB);
    f16* Kh = (f16*)(ws + 17 * MB);
    f16* Vt = (f16*)(ws + 21 * MB);
    float* pO = (float*)(ws + 25 * MB);
    float* pM = (float*)(ws + 57 * MB);
    float* pL = (float*)(ws + 57 * MB + 256 * 1024);
    (void)ws_size; (void)in_sizes; (void)n_in; (void)out_size;

    splitX_kernel<<<2048, 256, 0, stream>>>((const float4*)X, (f16x4*)Xh, (f16x4*)Xl);
    splitW_kernel<<<768, 256, 0, stream>>>(Wq, Wk, Wv, WtH, WtL);
    qkv_kernel<<<dim3(NN / 64, 3), 256, 0, stream>>>(Xh, Xl, WtH, WtL, Qh, Ql, Kh, Vt);
    flash_kernel<<<(NN / BR) * CCH, 256, 0, stream>>>(Qh, Ql, Kh, Vt, A, pO, pM, pL);
    merge_kernel<<<NN / 8, 256, 0, stream>>>(pO, pM, pL, out);
}

// Round 9
// 516.540 us; speedup vs baseline: 1.0789x; 1.0789x over previous
//
#include <hip/hip_runtime.h>
#include <stdint.h>

// GATConv fused v9 = v5 (best: 188us) + softmax diet ONLY.
// v5 structure untouched: 8-wave blocks, BR=128, dbuf K/V, ONE barrier/iter,
// wave-local softmax, P per-wave stride-72.
// Diet: packed-f16x2 max reduce (8 shfl, was 16), deferred l-sum (0 shfl/iter,
// was 16; one epilogue reduce). Validated in R6-R8 (absmax 0.080 passed).

typedef _Float16 f16;
typedef unsigned short u16;
typedef __attribute__((ext_vector_type(8))) _Float16 f16x8;
typedef __attribute__((ext_vector_type(4))) _Float16 f16x4;
typedef __attribute__((ext_vector_type(4))) float f32x4;

#define NN 8192
#define DD 256
#define BR 128
#define BC 64
#define CCH 4
#define COLS (NN / CCH)  // 2048
#define NIT (COLS / BC)  // 32

#define MFMA(a, b, c) __builtin_amdgcn_mfma_f32_16x16x32_f16((a), (b), (c), 0, 0, 0)

__device__ __forceinline__ void gl2lds16(const void* g, void* l) {
    __builtin_amdgcn_global_load_lds(
        (const __attribute__((address_space(1))) unsigned int*)g,
        (__attribute__((address_space(3))) unsigned int*)l, 16, 0, 0);
}

__device__ __forceinline__ u16 f16bits(f16 h) {
    union { f16 h; u16 u; } c;
    c.h = h;
    return c.u;
}

union F16x2U {
    unsigned u;
    struct { f16 lo, hi; } f;
};

// ---------------- split X to fp16 hi/lo (4 elems/thread) ----------------
__global__ void splitX_kernel(const float4* __restrict__ X, f16x4* __restrict__ Xh,
                              f16x4* __restrict__ Xl) {
    const int i = blockIdx.x * blockDim.x + threadIdx.x;  // 524288
    const float4 v = X[i];
    const f16 h0 = (f16)v.x, h1 = (f16)v.y, h2 = (f16)v.z, h3 = (f16)v.w;
    f16x4 H = {h0, h1, h2, h3};
    f16x4 L = {(f16)(v.x - (float)h0), (f16)(v.y - (float)h1), (f16)(v.z - (float)h2),
               (f16)(v.w - (float)h3)};
    Xh[i] = H;
    Xl[i] = L;
}

// W[k][n] (3 mats 256x256) -> Wt[(mat*256+n)][k] fp16 hi/lo (transposed)
__global__ void splitW_kernel(const float* __restrict__ Wq, const float* __restrict__ Wk,
                              const float* __restrict__ Wv, f16* __restrict__ WtH,
                              f16* __restrict__ WtL) {
    const int i = blockIdx.x * blockDim.x + threadIdx.x;  // 3*65536
    const int mat = i >> 16;
    const int k = (i >> 8) & 255;
    const int n = i & 255;
    const float* W = (mat == 0) ? Wq : ((mat == 1) ? Wk : Wv);
    const float v = W[k * 256 + n];
    const f16 h = (f16)v;
    const size_t o = (size_t)(mat * 256 + n) * 256 + k;
    WtH[o] = h;
    WtL[o] = (f16)(v - (float)h);
}

// ---------------- QKV GEMM: LDS-staged W chunks, X frags in registers ----------------
__global__ __launch_bounds__(256, 2) void qkv_kernel(
    const f16* __restrict__ Xh, const f16* __restrict__ Xl,
    const f16* __restrict__ WtH, const f16* __restrict__ WtL,
    f16* __restrict__ Qh, f16* __restrict__ Ql,
    f16* __restrict__ Kh, f16* __restrict__ Vt) {
    __shared__ f16 Wh[64 * 256];
    __shared__ f16 Wl[64 * 256];
    const int lane = threadIdx.x & 63;
    const int w = threadIdx.x >> 6;
    const int l15 = lane & 15;
    const int quad = lane >> 4;
    const int r0 = blockIdx.x * 64;
    const int mat = blockIdx.y;

    f16x8 xh[8], xl[8];
    const size_t xb = (size_t)(r0 + w * 16 + l15) * DD + quad * 8;
#pragma unroll
    for (int kc = 0; kc < 8; ++kc) {
        xh[kc] = *(const f16x8*)(Xh + xb + kc * 32);
        xl[kc] = *(const f16x8*)(Xl + xb + kc * 32);
    }
    const int orow = r0 + w * 16 + quad * 4;

#pragma unroll 1
    for (int c = 0; c < 4; ++c) {
        const int nb = mat * 256 + c * 64;
#pragma unroll
        for (int i = 0; i < 8; ++i) {
            const int r = w * 16 + i * 2 + (lane >> 5);
            gl2lds16(WtH + (size_t)(nb + r) * DD + (((lane & 31) ^ (r & 7)) * 8),
                     &Wh[(w * 16 + i * 2) * 256]);
        }
#pragma unroll
        for (int i = 0; i < 8; ++i) {
            const int r = w * 16 + i * 2 + (lane >> 5);
            gl2lds16(WtL + (size_t)(nb + r) * DD + (((lane & 31) ^ (r & 7)) * 8),
                     &Wl[(w * 16 + i * 2) * 256]);
        }
        __syncthreads();

        const f32x4 fzero = {0.f, 0.f, 0.f, 0.f};
        f32x4 acc[4];
#pragma unroll
        for (int nt = 0; nt < 4; ++nt) acc[nt] = fzero;
#pragma unroll
        for (int kc = 0; kc < 8; ++kc)
#pragma unroll
            for (int nt = 0; nt < 4; ++nt) {
                const int r = nt * 16 + l15;
                const int blk = (((kc * 4 + quad) ^ (r & 7)) * 8);
                const f16x8 wh = *(const f16x8*)&Wh[r * 256 + blk];
                const f16x8 wl = *(const f16x8*)&Wl[r * 256 + blk];
                acc[nt] = MFMA(xh[kc], wh, acc[nt]);
                acc[nt] = MFMA(xh[kc], wl, acc[nt]);
                acc[nt] = MFMA(xl[kc], wh, acc[nt]);
            }

        if (mat == 0) {
#pragma unroll
            for (int nt = 0; nt < 4; ++nt)
#pragma unroll
                for (int rg = 0; rg < 4; ++rg) {
                    const int col = c * 64 + nt * 16 + l15;
                    const float v = acc[nt][rg];
                    const f16 h = (f16)v;
                    Qh[(size_t)(orow + rg) * DD + col] = h;
                    Ql[(size_t)(orow + rg) * DD + col] = (f16)(v - (float)h);
                }
        } else if (mat == 1) {
#pragma unroll
            for (int nt = 0; nt < 4; ++nt)
#pragma unroll
                for (int rg = 0; rg < 4; ++rg) {
                    const int col = c * 64 + nt * 16 + l15;
                    Kh[(size_t)(orow + rg) * DD + col] = (f16)acc[nt][rg];
                }
        } else {
#pragma unroll
            for (int nt = 0; nt < 4; ++nt) {
                const int n = c * 64 + nt * 16 + l15;
                ushort4 pk;
                pk.x = f16bits((f16)acc[nt][0]);
                pk.y = f16bits((f16)acc[nt][1]);
                pk.z = f16bits((f16)acc[nt][2]);
                pk.w = f16bits((f16)acc[nt][3]);
                *(ushort4*)(Vt + (size_t)n * NN + orow) = pk;
            }
        }
        __syncthreads();
    }
}

// ---------------- flash kernel v9 (v5 + softmax diet) ----------------
// grid 256 linear: cch = bid&3 (pins chunk to XCD pair), rowblk = bid>>2, BR=128.
__global__ __launch_bounds__(512, 2) void flash_kernel(
    const f16* __restrict__ Qh, const f16* __restrict__ Ql,
    const f16* __restrict__ Kh, const f16* __restrict__ Vt,
    const int* __restrict__ A,
    float* __restrict__ pO, float* __restrict__ pM, float* __restrict__ pL) {
    __shared__ f16 Klds[2][64 * 256];  // 64 KB dbuf, [j][k] XOR-swizzled by j&7
    __shared__ f16 Vlds[2][256 * 64];  // 64 KB dbuf, [n][j] swizzled by n&7
    __shared__ f16 Plds[8][16 * 72];   // 18 KB, per-wave

    const int lane = threadIdx.x & 63;
    const int w = threadIdx.x >> 6;  // 0..7
    const int l15 = lane & 15;
    const int quad = lane >> 4;
    const int bid = blockIdx.x;
    const int cch = bid & 3;
    const int r0 = (bid >> 2) * BR;
    const int col0 = cch * COLS;

    // Q fragments resident (A-layout m=l15, k=quad*8+i), hi+lo
    f16x8 qh[8], ql[8];
    {
        const size_t qb = (size_t)(r0 + w * 16 + l15) * DD + quad * 8;
#pragma unroll
        for (int kc = 0; kc < 8; ++kc) {
            qh[kc] = *(const f16x8*)(Qh + qb + kc * 32);
            ql[kc] = *(const f16x8*)(Ql + qb + kc * 32);
        }
    }

    const f32x4 fzero = {0.f, 0.f, 0.f, 0.f};
    f32x4 accO[16];
#pragma unroll
    for (int i = 0; i < 16; ++i) accO[i] = fzero;
    float mrow[4], lpart[4];  // lpart: per-LANE partial sums, reduced in epilogue
#pragma unroll
    for (int r = 0; r < 4; ++r) {
        mrow[r] = -1e30f;
        lpart[r] = 0.f;
    }
    const int growb = r0 + w * 16 + quad * 4;
    f16* Pw = &Plds[w][0];

    // stage tile `t` into buffer `b` (each of 8 waves: 4 K-instrs + 4 V-instrs)
    auto stage = [&](int t, int b) {
        const int j0 = col0 + t * BC;
#pragma unroll
        for (int i = 0; i < 4; ++i) {
            const int r = w * 8 + i * 2 + (lane >> 5);
            gl2lds16(Kh + (size_t)(j0 + r) * DD + (((lane & 31) ^ (r & 7)) * 8),
                     &Klds[b][(w * 8 + i * 2) * 256]);
        }
#pragma unroll
        for (int i = 0; i < 4; ++i) {
            const int n = w * 32 + i * 8 + (lane >> 3);
            gl2lds16(Vt + (size_t)n * NN + j0 + (((lane & 7) ^ (n & 7)) * 8),
                     &Vlds[b][(w * 32 + i * 8) * 64]);
        }
    };

    // prologue: stage tile 0 -> buf 0
    stage(0, 0);
    __syncthreads();

#pragma unroll 1
    for (int it = 0; it < NIT; ++it) {
        const int cur = it & 1;
        const int j0 = col0 + it * BC;

        // stage NEXT tile into alternate buffer (covered by this iter's compute)
        if (it + 1 < NIT) stage(it + 1, cur ^ 1);

        // adjacency for this tile (nontemporal: streamed once)
        int av[4][4];
#pragma unroll
        for (int rgi = 0; rgi < 4; ++rgi)
#pragma unroll
            for (int jt = 0; jt < 4; ++jt)
                av[rgi][jt] = __builtin_nontemporal_load(
                    A + (size_t)(growb + rgi) * NN + j0 + jt * 16 + l15);

        // S = (Qh+Ql)·Kh^T : 16 rows x 64 cols per wave
        f32x4 accS[4];
#pragma unroll
        for (int jt = 0; jt < 4; ++jt) accS[jt] = fzero;
#pragma unroll
        for (int kc = 0; kc < 8; ++kc)
#pragma unroll
            for (int jt = 0; jt < 4; ++jt) {
                const int r = jt * 16 + l15;
                const f16x8 kf =
                    *(const f16x8*)&Klds[cur][r * 256 + (((kc * 4 + quad) ^ (r & 7)) * 8)];
                accS[jt] = MFMA(qh[kc], kf, accS[jt]);
                accS[jt] = MFMA(ql[kc], kf, accS[jt]);
            }

        // mask + per-lane jt-max
        float mx[4];
#pragma unroll
        for (int rgi = 0; rgi < 4; ++rgi) {
            const int gr = growb + rgi;
            float m = -3.0e38f;
#pragma unroll
            for (int jt = 0; jt < 4; ++jt) {
                const int gc = j0 + jt * 16 + l15;
                const float s = (av[rgi][jt] != 0 || gr == gc) ? accS[jt][rgi] : -3.0e38f;
                accS[jt][rgi] = s;
                m = fmaxf(m, s);
            }
            mx[rgi] = m;
        }
        // packed f16x2 max reduction over 16 lanes (2 chains instead of 4)
        // f16 rounding of the max is exactly compensated by normalization.
        {
            F16x2U a, b;
            a.f.lo = (f16)mx[0];
            a.f.hi = (f16)mx[1];
            b.f.lo = (f16)mx[2];
            b.f.hi = (f16)mx[3];
#pragma unroll
            for (int off = 1; off < 16; off <<= 1) {
                F16x2U as, bs;
                as.u = __shfl_xor(a.u, off, 64);
                bs.u = __shfl_xor(b.u, off, 64);
                a.f.lo = (as.f.lo > a.f.lo) ? as.f.lo : a.f.lo;
                a.f.hi = (as.f.hi > a.f.hi) ? as.f.hi : a.f.hi;
                b.f.lo = (bs.f.lo > b.f.lo) ? bs.f.lo : b.f.lo;
                b.f.hi = (bs.f.hi > b.f.hi) ? bs.f.hi : b.f.hi;
            }
            mx[0] = (float)a.f.lo;
            mx[1] = (float)a.f.hi;
            mx[2] = (float)b.f.lo;
            mx[3] = (float)b.f.hi;
        }

        float alpha[4];
#pragma unroll
        for (int rgi = 0; rgi < 4; ++rgi) {
            const float mnew = fmaxf(mrow[rgi], mx[rgi]);
            alpha[rgi] = __expf(mrow[rgi] - mnew);
            mrow[rgi] = mnew;
            float rs = 0.f;
#pragma unroll
            for (int jt = 0; jt < 4; ++jt) {
                const float s = accS[jt][rgi];
                const float e = (s > -1.0e37f) ? __expf(s - mnew) : 0.f;
                rs += e;
                Pw[(quad * 4 + rgi) * 72 + jt * 16 + l15] = (f16)e;
            }
            lpart[rgi] = lpart[rgi] * alpha[rgi] + rs;  // per-lane; reduced in epilogue
        }
#pragma unroll
        for (int nt = 0; nt < 16; ++nt)
#pragma unroll
            for (int rgi = 0; rgi < 4; ++rgi) accO[nt][rgi] *= alpha[rgi];

        // P A-frags (per-wave LDS round trip; in-order LDS pipe, no barrier)
        f16x8 pf[2];
        pf[0] = *(const f16x8*)&Pw[l15 * 72 + quad * 8];
        pf[1] = *(const f16x8*)&Pw[l15 * 72 + 32 + quad * 8];

        // PV: 16 rows x 256 n per wave
#pragma unroll
        for (int nt = 0; nt < 16; ++nt)
#pragma unroll
            for (int kc2 = 0; kc2 < 2; ++kc2) {
                const int n = nt * 16 + l15;
                const f16x8 vf =
                    *(const f16x8*)&Vlds[cur][n * 64 + (((kc2 * 4 + quad) ^ (n & 7)) * 8)];
                accO[nt] = MFMA(pf[kc2], vf, accO[nt]);
            }

        // single barrier: compute(it) done before buf overwrite; drains stage(it+1)
        __syncthreads();
    }

    // epilogue: reduce per-lane l partials across 16 lanes (once, not per iter)
#pragma unroll
    for (int rgi = 0; rgi < 4; ++rgi)
#pragma unroll
        for (int off = 1; off < 16; off <<= 1)
            lpart[rgi] += __shfl_xor(lpart[rgi], off, 64);

    // write partials
#pragma unroll
    for (int nt = 0; nt < 16; ++nt)
#pragma unroll
        for (int rgi = 0; rgi < 4; ++rgi)
            pO[((size_t)cch * NN + growb + rgi) * DD + nt * 16 + l15] = accO[nt][rgi];
    if (l15 == 0) {
#pragma unroll
        for (int rgi = 0; rgi < 4; ++rgi) {
            pM[(size_t)cch * NN + growb + rgi] = mrow[rgi];
            pL[(size_t)cch * NN + growb + rgi] = lpart[rgi];
        }
    }
}

// ---------------- merge partials (8 rows/block) ----------------
__global__ __launch_bounds__(256) void merge_kernel(const float* __restrict__ pO,
                                                    const float* __restrict__ pM,
                                                    const float* __restrict__ pL,
                                                    float* __restrict__ out) {
    const int n = threadIdx.x;
#pragma unroll 1
    for (int rr = 0; rr < 8; ++rr) {
        const int row = blockIdx.x * 8 + rr;
        float mc[CCH], lc[CCH];
        float M = -3e38f;
#pragma unroll
        for (int c = 0; c < CCH; ++c) {
            mc[c] = pM[(size_t)c * NN + row];
            lc[c] = pL[(size_t)c * NN + row];
            M = fmaxf(M, mc[c]);
        }
        float L = 0.f, acc = 0.f;
#pragma unroll
        for (int c = 0; c < CCH; ++c) {
            const float wgt = __expf(mc[c] - M);
            L += wgt * lc[c];
            acc += wgt * pO[((size_t)c * NN + row) * DD + n];
        }
        out[(size_t)row * DD + n] = acc / L;
    }
}

extern "C" void kernel_launch(void* const* d_in, const int* in_sizes, int n_in,
                              void* d_out, int out_size, void* d_ws, size_t ws_size,
                              hipStream_t stream) {
    const float* X = (const float*)d_in[0];
    const int* A = (const int*)d_in[1];
    const float* Wq = (const float*)d_in[2];
    const float* Wk = (const float*)d_in[3];
    const float* Wv = (const float*)d_in[4];
    float* out = (float*)d_out;

    char* ws = (char*)d_ws;
    const size_t MB = 1ull << 20;
    f16* Xh = (f16*)(ws + 0 * MB);
    f16* Xl = (f16*)(ws + 4 * MB);
    f16* WtH = (f16*)(ws + 8 * MB);
    f16* WtL = (f16*)(ws + 8 * MB + 512 * 1024);
    f16* Qh = (f16*)(ws + 9 * MB);
    f16* Ql = (f16*)(ws + 13 * MB);
    f16* Kh = (f16*)(ws + 17 * MB);
    f16* Vt = (f16*)(ws + 21 * MB);
    float* pO = (float*)(ws + 25 * MB);
    float* pM = (float*)(ws + 57 * MB);
    float* pL = (float*)(ws + 57 * MB + 256 * 1024);
    (void)ws_size; (void)in_sizes; (void)n_in; (void)out_size;

    splitX_kernel<<<2048, 256, 0, stream>>>((const float4*)X, (f16x4*)Xh, (f16x4*)Xl);
    splitW_kernel<<<768, 256, 0, stream>>>(Wq, Wk, Wv, WtH, WtL);
    qkv_kernel<<<dim3(NN / 64, 3), 256, 0, stream>>>(Xh, Xl, WtH, WtL, Qh, Ql, Kh, Vt);
    flash_kernel<<<(NN / BR) * CCH, 512, 0, stream>>>(Qh, Ql, Kh, Vt, A, pO, pM, pL);
    merge_kernel<<<NN / 8, 256, 0, stream>>>(pO, pM, pL, out);
}

// Round 10
// 496.205 us; speedup vs baseline: 1.1231x; 1.0410x over previous
//
#include <hip/hip_runtime.h>
#include <stdint.h>

// GATConv fused v10 = v5 (best, 188us) + two local fixes:
//  (1) deferred l-sum: per-lane partials, one epilogue reduce (-16 shfl/iter,
//      adds nothing serial). [R9 regression isolated to the packed-f16 max,
//      which added ~56 serial VALU ops -- reverted to v5's f32 shfl max.]
//  (2) P stride 72 -> 80 f16 (40 dwords): quad groups land on banks
//      {0,8,16,24}, no overlap with the 8-dword lane span -> kills the
//      4-way P-write conflict (8.9M -> ~5-6M predicted).

typedef _Float16 f16;
typedef unsigned short u16;
typedef __attribute__((ext_vector_type(8))) _Float16 f16x8;
typedef __attribute__((ext_vector_type(4))) _Float16 f16x4;
typedef __attribute__((ext_vector_type(4))) float f32x4;

#define NN 8192
#define DD 256
#define BR 128
#define BC 64
#define CCH 4
#define COLS (NN / CCH)  // 2048
#define NIT (COLS / BC)  // 32
#define PSTR 80          // P row stride in f16 (40 dwords; bank-clean)

#define MFMA(a, b, c) __builtin_amdgcn_mfma_f32_16x16x32_f16((a), (b), (c), 0, 0, 0)

__device__ __forceinline__ void gl2lds16(const void* g, void* l) {
    __builtin_amdgcn_global_load_lds(
        (const __attribute__((address_space(1))) unsigned int*)g,
        (__attribute__((address_space(3))) unsigned int*)l, 16, 0, 0);
}

__device__ __forceinline__ u16 f16bits(f16 h) {
    union { f16 h; u16 u; } c;
    c.h = h;
    return c.u;
}

// ---------------- split X to fp16 hi/lo (4 elems/thread) ----------------
__global__ void splitX_kernel(const float4* __restrict__ X, f16x4* __restrict__ Xh,
                              f16x4* __restrict__ Xl) {
    const int i = blockIdx.x * blockDim.x + threadIdx.x;  // 524288
    const float4 v = X[i];
    const f16 h0 = (f16)v.x, h1 = (f16)v.y, h2 = (f16)v.z, h3 = (f16)v.w;
    f16x4 H = {h0, h1, h2, h3};
    f16x4 L = {(f16)(v.x - (float)h0), (f16)(v.y - (float)h1), (f16)(v.z - (float)h2),
               (f16)(v.w - (float)h3)};
    Xh[i] = H;
    Xl[i] = L;
}

// W[k][n] (3 mats 256x256) -> Wt[(mat*256+n)][k] fp16 hi/lo (transposed)
__global__ void splitW_kernel(const float* __restrict__ Wq, const float* __restrict__ Wk,
                              const float* __restrict__ Wv, f16* __restrict__ WtH,
                              f16* __restrict__ WtL) {
    const int i = blockIdx.x * blockDim.x + threadIdx.x;  // 3*65536
    const int mat = i >> 16;
    const int k = (i >> 8) & 255;
    const int n = i & 255;
    const float* W = (mat == 0) ? Wq : ((mat == 1) ? Wk : Wv);
    const float v = W[k * 256 + n];
    const f16 h = (f16)v;
    const size_t o = (size_t)(mat * 256 + n) * 256 + k;
    WtH[o] = h;
    WtL[o] = (f16)(v - (float)h);
}

// ---------------- QKV GEMM: LDS-staged W chunks, X frags in registers ----------------
__global__ __launch_bounds__(256, 2) void qkv_kernel(
    const f16* __restrict__ Xh, const f16* __restrict__ Xl,
    const f16* __restrict__ WtH, const f16* __restrict__ WtL,
    f16* __restrict__ Qh, f16* __restrict__ Ql,
    f16* __restrict__ Kh, f16* __restrict__ Vt) {
    __shared__ f16 Wh[64 * 256];
    __shared__ f16 Wl[64 * 256];
    const int lane = threadIdx.x & 63;
    const int w = threadIdx.x >> 6;
    const int l15 = lane & 15;
    const int quad = lane >> 4;
    const int r0 = blockIdx.x * 64;
    const int mat = blockIdx.y;

    f16x8 xh[8], xl[8];
    const size_t xb = (size_t)(r0 + w * 16 + l15) * DD + quad * 8;
#pragma unroll
    for (int kc = 0; kc < 8; ++kc) {
        xh[kc] = *(const f16x8*)(Xh + xb + kc * 32);
        xl[kc] = *(const f16x8*)(Xl + xb + kc * 32);
    }
    const int orow = r0 + w * 16 + quad * 4;

#pragma unroll 1
    for (int c = 0; c < 4; ++c) {
        const int nb = mat * 256 + c * 64;
#pragma unroll
        for (int i = 0; i < 8; ++i) {
            const int r = w * 16 + i * 2 + (lane >> 5);
            gl2lds16(WtH + (size_t)(nb + r) * DD + (((lane & 31) ^ (r & 7)) * 8),
                     &Wh[(w * 16 + i * 2) * 256]);
        }
#pragma unroll
        for (int i = 0; i < 8; ++i) {
            const int r = w * 16 + i * 2 + (lane >> 5);
            gl2lds16(WtL + (size_t)(nb + r) * DD + (((lane & 31) ^ (r & 7)) * 8),
                     &Wl[(w * 16 + i * 2) * 256]);
        }
        __syncthreads();

        const f32x4 fzero = {0.f, 0.f, 0.f, 0.f};
        f32x4 acc[4];
#pragma unroll
        for (int nt = 0; nt < 4; ++nt) acc[nt] = fzero;
#pragma unroll
        for (int kc = 0; kc < 8; ++kc)
#pragma unroll
            for (int nt = 0; nt < 4; ++nt) {
                const int r = nt * 16 + l15;
                const int blk = (((kc * 4 + quad) ^ (r & 7)) * 8);
                const f16x8 wh = *(const f16x8*)&Wh[r * 256 + blk];
                const f16x8 wl = *(const f16x8*)&Wl[r * 256 + blk];
                acc[nt] = MFMA(xh[kc], wh, acc[nt]);
                acc[nt] = MFMA(xh[kc], wl, acc[nt]);
                acc[nt] = MFMA(xl[kc], wh, acc[nt]);
            }

        if (mat == 0) {
#pragma unroll
            for (int nt = 0; nt < 4; ++nt)
#pragma unroll
                for (int rg = 0; rg < 4; ++rg) {
                    const int col = c * 64 + nt * 16 + l15;
                    const float v = acc[nt][rg];
                    const f16 h = (f16)v;
                    Qh[(size_t)(orow + rg) * DD + col] = h;
                    Ql[(size_t)(orow + rg) * DD + col] = (f16)(v - (float)h);
                }
        } else if (mat == 1) {
#pragma unroll
            for (int nt = 0; nt < 4; ++nt)
#pragma unroll
                for (int rg = 0; rg < 4; ++rg) {
                    const int col = c * 64 + nt * 16 + l15;
                    Kh[(size_t)(orow + rg) * DD + col] = (f16)acc[nt][rg];
                }
        } else {
#pragma unroll
            for (int nt = 0; nt < 4; ++nt) {
                const int n = c * 64 + nt * 16 + l15;
                ushort4 pk;
                pk.x = f16bits((f16)acc[nt][0]);
                pk.y = f16bits((f16)acc[nt][1]);
                pk.z = f16bits((f16)acc[nt][2]);
                pk.w = f16bits((f16)acc[nt][3]);
                *(ushort4*)(Vt + (size_t)n * NN + orow) = pk;
            }
        }
        __syncthreads();
    }
}

// ---------------- flash kernel v10 (v5 + deferred l-sum + P stride 80) ----------------
// grid 256 linear: cch = bid&3 (pins chunk to XCD pair), rowblk = bid>>2, BR=128.
__global__ __launch_bounds__(512, 2) void flash_kernel(
    const f16* __restrict__ Qh, const f16* __restrict__ Ql,
    const f16* __restrict__ Kh, const f16* __restrict__ Vt,
    const int* __restrict__ A,
    float* __restrict__ pO, float* __restrict__ pM, float* __restrict__ pL) {
    __shared__ f16 Klds[2][64 * 256];   // 64 KB dbuf, [j][k] XOR-swizzled by j&7
    __shared__ f16 Vlds[2][256 * 64];   // 64 KB dbuf, [n][j] swizzled by n&7
    __shared__ f16 Plds[8][16 * PSTR];  // 20 KB, per-wave, stride 80 (bank-clean)

    const int lane = threadIdx.x & 63;
    const int w = threadIdx.x >> 6;  // 0..7
    const int l15 = lane & 15;
    const int quad = lane >> 4;
    const int bid = blockIdx.x;
    const int cch = bid & 3;
    const int r0 = (bid >> 2) * BR;
    const int col0 = cch * COLS;

    // Q fragments resident (A-layout m=l15, k=quad*8+i), hi+lo
    f16x8 qh[8], ql[8];
    {
        const size_t qb = (size_t)(r0 + w * 16 + l15) * DD + quad * 8;
#pragma unroll
        for (int kc = 0; kc < 8; ++kc) {
            qh[kc] = *(const f16x8*)(Qh + qb + kc * 32);
            ql[kc] = *(const f16x8*)(Ql + qb + kc * 32);
        }
    }

    const f32x4 fzero = {0.f, 0.f, 0.f, 0.f};
    f32x4 accO[16];
#pragma unroll
    for (int i = 0; i < 16; ++i) accO[i] = fzero;
    float mrow[4], lpart[4];  // lpart: per-LANE partials, reduced in epilogue
#pragma unroll
    for (int r = 0; r < 4; ++r) {
        mrow[r] = -1e30f;
        lpart[r] = 0.f;
    }
    const int growb = r0 + w * 16 + quad * 4;
    f16* Pw = &Plds[w][0];

    // stage tile `t` into buffer `b` (each of 8 waves: 4 K-instrs + 4 V-instrs)
    auto stage = [&](int t, int b) {
        const int j0 = col0 + t * BC;
#pragma unroll
        for (int i = 0; i < 4; ++i) {
            const int r = w * 8 + i * 2 + (lane >> 5);
            gl2lds16(Kh + (size_t)(j0 + r) * DD + (((lane & 31) ^ (r & 7)) * 8),
                     &Klds[b][(w * 8 + i * 2) * 256]);
        }
#pragma unroll
        for (int i = 0; i < 4; ++i) {
            const int n = w * 32 + i * 8 + (lane >> 3);
            gl2lds16(Vt + (size_t)n * NN + j0 + (((lane & 7) ^ (n & 7)) * 8),
                     &Vlds[b][(w * 32 + i * 8) * 64]);
        }
    };

    // prologue: stage tile 0 -> buf 0
    stage(0, 0);
    __syncthreads();

#pragma unroll 1
    for (int it = 0; it < NIT; ++it) {
        const int cur = it & 1;
        const int j0 = col0 + it * BC;

        // stage NEXT tile into alternate buffer (covered by this iter's compute)
        if (it + 1 < NIT) stage(it + 1, cur ^ 1);

        // adjacency for this tile (nontemporal: streamed once)
        int av[4][4];
#pragma unroll
        for (int rgi = 0; rgi < 4; ++rgi)
#pragma unroll
            for (int jt = 0; jt < 4; ++jt)
                av[rgi][jt] = __builtin_nontemporal_load(
                    A + (size_t)(growb + rgi) * NN + j0 + jt * 16 + l15);

        // S = (Qh+Ql)·Kh^T : 16 rows x 64 cols per wave
        f32x4 accS[4];
#pragma unroll
        for (int jt = 0; jt < 4; ++jt) accS[jt] = fzero;
#pragma unroll
        for (int kc = 0; kc < 8; ++kc)
#pragma unroll
            for (int jt = 0; jt < 4; ++jt) {
                const int r = jt * 16 + l15;
                const f16x8 kf =
                    *(const f16x8*)&Klds[cur][r * 256 + (((kc * 4 + quad) ^ (r & 7)) * 8)];
                accS[jt] = MFMA(qh[kc], kf, accS[jt]);
                accS[jt] = MFMA(ql[kc], kf, accS[jt]);
            }

        // wave-local online softmax (f32 shfl max, as v5; l-sum deferred)
        float alpha[4];
#pragma unroll
        for (int rgi = 0; rgi < 4; ++rgi) {
            const int gr = growb + rgi;
            float mx = -3.0e38f;
#pragma unroll
            for (int jt = 0; jt < 4; ++jt) {
                const int gc = j0 + jt * 16 + l15;
                const float s = (av[rgi][jt] != 0 || gr == gc) ? accS[jt][rgi] : -3.0e38f;
                accS[jt][rgi] = s;
                mx = fmaxf(mx, s);
            }
#pragma unroll
            for (int off = 1; off < 16; off <<= 1) mx = fmaxf(mx, __shfl_xor(mx, off, 64));
            const float mnew = fmaxf(mrow[rgi], mx);
            alpha[rgi] = __expf(mrow[rgi] - mnew);
            mrow[rgi] = mnew;
            float rs = 0.f;
#pragma unroll
            for (int jt = 0; jt < 4; ++jt) {
                const float s = accS[jt][rgi];
                const float e = (s > -1.0e37f) ? __expf(s - mnew) : 0.f;
                rs += e;
                Pw[(quad * 4 + rgi) * PSTR + jt * 16 + l15] = (f16)e;
            }
            lpart[rgi] = lpart[rgi] * alpha[rgi] + rs;  // per-lane; epilogue reduce
        }
#pragma unroll
        for (int nt = 0; nt < 16; ++nt)
#pragma unroll
            for (int rgi = 0; rgi < 4; ++rgi) accO[nt][rgi] *= alpha[rgi];

        // P A-frags (per-wave LDS round trip; in-order LDS pipe, no barrier)
        f16x8 pf[2];
        pf[0] = *(const f16x8*)&Pw[l15 * PSTR + quad * 8];
        pf[1] = *(const f16x8*)&Pw[l15 * PSTR + 32 + quad * 8];

        // PV: 16 rows x 256 n per wave
#pragma unroll
        for (int nt = 0; nt < 16; ++nt)
#pragma unroll
            for (int kc2 = 0; kc2 < 2; ++kc2) {
                const int n = nt * 16 + l15;
                const f16x8 vf =
                    *(const f16x8*)&Vlds[cur][n * 64 + (((kc2 * 4 + quad) ^ (n & 7)) * 8)];
                accO[nt] = MFMA(pf[kc2], vf, accO[nt]);
            }

        // single barrier: compute(it) done before buf overwrite; drains stage(it+1)
        __syncthreads();
    }

    // epilogue: reduce per-lane l partials across 16 lanes (once)
#pragma unroll
    for (int rgi = 0; rgi < 4; ++rgi)
#pragma unroll
        for (int off = 1; off < 16; off <<= 1)
            lpart[rgi] += __shfl_xor(lpart[rgi], off, 64);

    // write partials
#pragma unroll
    for (int nt = 0; nt < 16; ++nt)
#pragma unroll
        for (int rgi = 0; rgi < 4; ++rgi)
            pO[((size_t)cch * NN + growb + rgi) * DD + nt * 16 + l15] = accO[nt][rgi];
    if (l15 == 0) {
#pragma unroll
        for (int rgi = 0; rgi < 4; ++rgi) {
            pM[(size_t)cch * NN + growb + rgi] = mrow[rgi];
            pL[(size_t)cch * NN + growb + rgi] = lpart[rgi];
        }
    }
}

// ---------------- merge partials (8 rows/block) ----------------
__global__ __launch_bounds__(256) void merge_kernel(const float* __restrict__ pO,
                                                    const float* __restrict__ pM,
                                                    const float* __restrict__ pL,
                                                    float* __restrict__ out) {
    const int n = threadIdx.x;
#pragma unroll 1
    for (int rr = 0; rr < 8; ++rr) {
        const int row = blockIdx.x * 8 + rr;
        float mc[CCH], lc[CCH];
        float M = -3e38f;
#pragma unroll
        for (int c = 0; c < CCH; ++c) {
            mc[c] = pM[(size_t)c * NN + row];
            lc[c] = pL[(size_t)c * NN + row];
            M = fmaxf(M, mc[c]);
        }
        float L = 0.f, acc = 0.f;
#pragma unroll
        for (int c = 0; c < CCH; ++c) {
            const float wgt = __expf(mc[c] - M);
            L += wgt * lc[c];
            acc += wgt * pO[((size_t)c * NN + row) * DD + n];
        }
        out[(size_t)row * DD + n] = acc / L;
    }
}

extern "C" void kernel_launch(void* const* d_in, const int* in_sizes, int n_in,
                              void* d_out, int out_size, void* d_ws, size_t ws_size,
                              hipStream_t stream) {
    const float* X = (const float*)d_in[0];
    const int* A = (const int*)d_in[1];
    const float* Wq = (const float*)d_in[2];
    const float* Wk = (const float*)d_in[3];
    const float* Wv = (const float*)d_in[4];
    float* out = (float*)d_out;

    char* ws = (char*)d_ws;
    const size_t MB = 1ull << 20;
    f16* Xh = (f16*)(ws + 0 * MB);
    f16* Xl = (f16*)(ws + 4 * MB);
    f16* WtH = (f16*)(ws + 8 * MB);
    f16* WtL = (f16*)(ws + 8 * MB + 512 * 1024);
    f16* Qh = (f16*)(ws + 9 * MB);
    f16* Ql = (f16*)(ws + 13 * MB);
    f16* Kh = (f16*)(ws + 17 * MB);
    f16* Vt = (f16*)(ws + 21 * MB);
    float* pO = (float*)(ws + 25 * MB);
    float* pM = (float*)(ws + 57 * MB);
    float* pL = (float*)(ws + 57 * MB + 256 * 1024);
    (void)ws_size; (void)in_sizes; (void)n_in; (void)out_size;

    splitX_kernel<<<2048, 256, 0, stream>>>((const float4*)X, (f16x4*)Xh, (f16x4*)Xl);
    splitW_kernel<<<768, 256, 0, stream>>>(Wq, Wk, Wv, WtH, WtL);
    qkv_kernel<<<dim3(NN / 64, 3), 256, 0, stream>>>(Xh, Xl, WtH, WtL, Qh, Ql, Kh, Vt);
    flash_kernel<<<(NN / BR) * CCH, 512, 0, stream>>>(Qh, Ql, Kh, Vt, A, pO, pM, pL);
    merge_kernel<<<NN / 8, 256, 0, stream>>>(pO, pM, pL, out);
}